// Round 1
// baseline (506.871 us; speedup 1.0000x reference)
//
#include <hip/hip_runtime.h>

// VQ: z [32,256,32,32] f32, codebook [1024,256] f32
// out: z_q [32,256,32,32] f32 (8388608) then loss scalar f32 (1)
#define B_  32
#define C_  256
#define HW_ 1024          // 32*32
#define K_  1024
#define N_  (B_*HW_)      // 32768
#define NELEM 8388608     // B*C*HW

// ---------------------------------------------------------------------------
// Kernel 1: codebook squared norms. One wave per code (4 waves/block).
__global__ __launch_bounds__(256) void cnorm_kernel(const float* __restrict__ cb,
                                                    float* __restrict__ cn) {
    int wave = threadIdx.x >> 6;
    int lane = threadIdx.x & 63;
    int k = blockIdx.x * 4 + wave;              // grid=256 -> k in [0,1024)
    float4 v = *(const float4*)(cb + (size_t)k * C_ + lane * 4);
    float s = v.x * v.x + v.y * v.y + v.z * v.z + v.w * v.w;
    #pragma unroll
    for (int off = 32; off; off >>= 1) s += __shfl_down(s, off, 64);
    if (lane == 0) cn[k] = s;
}

// ---------------------------------------------------------------------------
// Kernel 2: distance argmin.  Block = 64 positions x all 1024 codes.
// dist_rel[k] = ||c_k||^2 - 2*dot(z, c_k)   (||z||^2 dropped: constant in k)
// A-tile (64 pos x 256 c) resident in LDS (64 KB); B loaded in 64-code x 32-c
// chunks. 256 threads, each computes a 4x4 (pos x code) register tile.
#define TN 64
#define TK 64
#define TCC 32

__global__ __launch_bounds__(256, 2) void argmin_kernel(
        const float* __restrict__ z, const float* __restrict__ cb,
        const float* __restrict__ cn, int* __restrict__ idx) {
    __shared__ float Asm[C_][TN];               // [c][pos], 64 KB
    __shared__ union {
        float B[TCC][TK];                       // [c_local][code], 8 KB
        struct { float Rv[TN][16]; int Ri[TN][16]; } red;   // 8 KB
    } U;

    const int t   = threadIdx.x;
    const int blk = blockIdx.x;                 // 512 blocks
    const int b   = blk >> 4;
    const int hw0 = (blk & 15) << 6;
    const float* zb = z + ((size_t)b * C_) * HW_ + hw0;

    // Load A-tile: 256 c x 64 pos, coalesced float4 (16 per thread).
    #pragma unroll
    for (int r = 0; r < 16; ++r) {
        int f = r * 256 + t;                    // float4 index 0..4095
        int c = f >> 4;
        int p = (f & 15) << 2;
        *(float4*)(&Asm[c][p]) = *(const float4*)(zb + (size_t)c * HW_ + p);
    }

    const int tx = t & 15;                      // position group (4 pos)
    const int ty = t >> 4;                      // code group (4 codes)

    float minv[4];
    int   mini[4];
    #pragma unroll
    for (int i = 0; i < 4; ++i) { minv[i] = 3.4e38f; mini[i] = 0; }

    for (int kt = 0; kt < K_; kt += TK) {
        float acc[4][4] = {};
        for (int cc = 0; cc < C_; cc += TCC) {
            __syncthreads();                    // protect U.B readers / A-tile on first pass
            {   // load B chunk: codes kt..kt+63, channels cc..cc+31 (transposed store)
                int j  = t >> 2;
                int cg = t & 3;
                const float* src = cb + (size_t)(kt + j) * C_ + cc + cg * 8;
                float4 v0 = *(const float4*)(src);
                float4 v1 = *(const float4*)(src + 4);
                int c0 = cg * 8;
                U.B[c0 + 0][j] = v0.x; U.B[c0 + 1][j] = v0.y;
                U.B[c0 + 2][j] = v0.z; U.B[c0 + 3][j] = v0.w;
                U.B[c0 + 4][j] = v1.x; U.B[c0 + 5][j] = v1.y;
                U.B[c0 + 6][j] = v1.z; U.B[c0 + 7][j] = v1.w;
            }
            __syncthreads();
            #pragma unroll
            for (int s = 0; s < TCC; ++s) {
                float4 a  = *(const float4*)(&Asm[cc + s][tx << 2]);
                float4 bv = *(const float4*)(&U.B[s][ty << 2]);
                acc[0][0] += a.x * bv.x; acc[0][1] += a.x * bv.y;
                acc[0][2] += a.x * bv.z; acc[0][3] += a.x * bv.w;
                acc[1][0] += a.y * bv.x; acc[1][1] += a.y * bv.y;
                acc[1][2] += a.y * bv.z; acc[1][3] += a.y * bv.w;
                acc[2][0] += a.z * bv.x; acc[2][1] += a.z * bv.y;
                acc[2][2] += a.z * bv.z; acc[2][3] += a.z * bv.w;
                acc[3][0] += a.w * bv.x; acc[3][1] += a.w * bv.y;
                acc[3][2] += a.w * bv.z; acc[3][3] += a.w * bv.w;
            }
        }
        // dist = cn[k] - 2*dot ; running min, earliest index wins ties (k ascending)
        float4 cnv = *(const float4*)(cn + kt + (ty << 2));
        int kbase = kt + (ty << 2);
        #pragma unroll
        for (int i = 0; i < 4; ++i) {
            float d0 = cnv.x - 2.0f * acc[i][0];
            float d1 = cnv.y - 2.0f * acc[i][1];
            float d2 = cnv.z - 2.0f * acc[i][2];
            float d3 = cnv.w - 2.0f * acc[i][3];
            if (d0 < minv[i]) { minv[i] = d0; mini[i] = kbase + 0; }
            if (d1 < minv[i]) { minv[i] = d1; mini[i] = kbase + 1; }
            if (d2 < minv[i]) { minv[i] = d2; mini[i] = kbase + 2; }
            if (d3 < minv[i]) { minv[i] = d3; mini[i] = kbase + 3; }
        }
    }

    // Cross-ty reduction: 16 candidates per position.
    __syncthreads();
    #pragma unroll
    for (int i = 0; i < 4; ++i) {
        U.red.Rv[(tx << 2) + i][ty] = minv[i];
        U.red.Ri[(tx << 2) + i][ty] = mini[i];
    }
    __syncthreads();
    if (t < TN) {
        float bv = U.red.Rv[t][0];
        int   bi = U.red.Ri[t][0];
        #pragma unroll
        for (int y = 1; y < 16; ++y) {
            float v = U.red.Rv[t][y];
            int   ii = U.red.Ri[t][y];
            if (v < bv || (v == bv && ii < bi)) { bv = v; bi = ii; }
        }
        idx[blk * TN + t] = bi;                 // n = b*1024 + hw0 + t
    }
}

// ---------------------------------------------------------------------------
// Kernel 3: z_q scatter (coalesced in output layout) + exact loss.
// loss = 1.25 * mean((codebook[idx] - z)^2), accumulated block-wise.
__global__ __launch_bounds__(256) void scatter_kernel(
        const float* __restrict__ z, const float* __restrict__ cb,
        const int* __restrict__ idx, float* __restrict__ out,
        float* __restrict__ loss) {
    size_t base = ((size_t)blockIdx.x * 256 + threadIdx.x) * 4;
    int b  = (int)(base >> 18);
    int c  = (int)((base >> 10) & 255);
    int n  = (b << 10) + (int)(base & 1023);
    int4 iv = *(const int4*)(idx + n);
    float4 zv = *(const float4*)(z + base);
    float4 q;
    q.x = cb[(size_t)iv.x * C_ + c];
    q.y = cb[(size_t)iv.y * C_ + c];
    q.z = cb[(size_t)iv.z * C_ + c];
    q.w = cb[(size_t)iv.w * C_ + c];
    *(float4*)(out + base) = q;                 // straight-through: z + (q - z) == q
    float dx = q.x - zv.x, dy = q.y - zv.y, dz = q.z - zv.z, dw = q.w - zv.w;
    float s = dx * dx + dy * dy + dz * dz + dw * dw;
    #pragma unroll
    for (int off = 32; off; off >>= 1) s += __shfl_down(s, off, 64);
    __shared__ float wsum[4];
    int lane = threadIdx.x & 63, wv = threadIdx.x >> 6;
    if (lane == 0) wsum[wv] = s;
    __syncthreads();
    if (threadIdx.x == 0) {
        float tot = wsum[0] + wsum[1] + wsum[2] + wsum[3];
        atomicAdd(loss, tot * (1.25f / (float)NELEM));
    }
}

// ---------------------------------------------------------------------------
extern "C" void kernel_launch(void* const* d_in, const int* in_sizes, int n_in,
                              void* d_out, int out_size, void* d_ws, size_t ws_size,
                              hipStream_t stream) {
    const float* z  = (const float*)d_in[0];
    const float* cb = (const float*)d_in[1];
    float* out  = (float*)d_out;
    float* cn   = (float*)d_ws;                     // 1024 floats
    int*   idx  = (int*)((float*)d_ws + K_);        // 32768 ints
    float* loss = out + NELEM;

    hipMemsetAsync(loss, 0, sizeof(float), stream); // harness re-poisons d_out
    cnorm_kernel<<<K_ / 4, 256, 0, stream>>>(cb, cn);
    argmin_kernel<<<N_ / TN, 256, 0, stream>>>(z, cb, cn, idx);
    scatter_kernel<<<NELEM / 4 / 256, 256, 0, stream>>>(z, cb, idx, out, loss);
}

// Round 2
// 126.769 us; speedup vs baseline: 3.9984x; 3.9984x over previous
//
#include <hip/hip_runtime.h>

// VQ: z [32,256,32,32] f32, codebook [1024,256] f32
// out: z_q [32,256,32,32] f32 (8388608) then loss scalar f32 (1)
#define B_  32
#define C_  256
#define HW_ 1024
#define K_  1024
#define N_  (B_*HW_)
#define NELEM 8388608

typedef __attribute__((ext_vector_type(8))) short short8;   // 8 bf16 (4 VGPR)
typedef __attribute__((ext_vector_type(4))) float f32x4;

// ---------------------------------------------------------------------------
// Kernel 1: codebook squared norms (fp32, exact). One wave per code.
__global__ __launch_bounds__(256) void cnorm_kernel(const float* __restrict__ cb,
                                                    float* __restrict__ cn) {
    int wave = threadIdx.x >> 6;
    int lane = threadIdx.x & 63;
    int k = blockIdx.x * 4 + wave;
    float4 v = *(const float4*)(cb + (size_t)k * C_ + lane * 4);
    float s = v.x * v.x + v.y * v.y + v.z * v.z + v.w * v.w;
    #pragma unroll
    for (int off = 32; off; off >>= 1) s += __shfl_down(s, off, 64);
    if (lane == 0) cn[k] = s;
}

// ---------------------------------------------------------------------------
// Kernel 2: codebook -> bf16 in B-fragment-linear order.
// frag g = (nt*8+ks)*64 + L holds cb[nt*16 + (L&15)][ks*32 + (L>>4)*8 + 0..7]
__global__ __launch_bounds__(256) void prep_cb(const float* __restrict__ cb,
                                               uint4* __restrict__ cbf) {
    int g  = blockIdx.x * 256 + threadIdx.x;      // 0..32767
    int L  = g & 63, ks = (g >> 6) & 7, nt = g >> 9;
    int code = nt * 16 + (L & 15);
    int k0   = ks * 32 + (L >> 4) * 8;
    const unsigned* s = (const unsigned*)(cb + (size_t)code * C_ + k0);
    unsigned a0 = s[0], a1 = s[1], a2 = s[2], a3 = s[3];
    unsigned b0 = s[4], b1 = s[5], b2 = s[6], b3 = s[7];
    uint4 o;
    o.x = ((a0 + 0x8000u) >> 16) | ((a1 + 0x8000u) & 0xffff0000u);
    o.y = ((a2 + 0x8000u) >> 16) | ((a3 + 0x8000u) & 0xffff0000u);
    o.z = ((b0 + 0x8000u) >> 16) | ((b1 + 0x8000u) & 0xffff0000u);
    o.w = ((b2 + 0x8000u) >> 16) | ((b3 + 0x8000u) & 0xffff0000u);
    cbf[g] = o;
}

// ---------------------------------------------------------------------------
// Kernel 3: MFMA argmin. Grid 256 blocks x 256 thr. Block = 128 pos x 1024
// codes, K=256 resident. A in LDS once -> registers; B-frags streamed from
// pre-swizzled global (L2). dist = cn[k] - 2*dot. nt packed in mantissa LSBs.
__global__ __launch_bounds__(256, 1) void argmin_mfma(
        const float* __restrict__ z, const char* __restrict__ cbfraw,
        const float* __restrict__ cn, int* __restrict__ idx) {
    __shared__ short Asm[128][264];               // pos x k bf16, padded
    __shared__ float cnS[K_];

    const int t = threadIdx.x, w = t >> 6, L = t & 63;
    const int blk = blockIdx.x;
    const int b = blk >> 3, hw0 = (blk & 7) << 7;
    const float* zb = z + ((size_t)b << 18) + hw0;

    // stage cn
    *(float4*)&cnS[t * 4] = *(const float4*)(cn + t * 4);

    // stage A: wave covers 64 pos x 128 c; thread handles 8 consecutive c of
    // one pos per iter (coalesced dword loads across pos, one b128 LDS write).
    {
        const int p  = ((w & 1) << 6) + L;
        const int ch = (w >> 1) << 7;
        const unsigned* zp = (const unsigned*)(zb + p);
        for (int it = 0; it < 16; ++it) {
            int c0 = ch + it * 8;
            const unsigned* s = zp + (c0 << 10);
            unsigned v[8];
            #pragma unroll
            for (int j = 0; j < 8; ++j) v[j] = s[j << 10];
            uint4 o;
            o.x = ((v[0] + 0x8000u) >> 16) | ((v[1] + 0x8000u) & 0xffff0000u);
            o.y = ((v[2] + 0x8000u) >> 16) | ((v[3] + 0x8000u) & 0xffff0000u);
            o.z = ((v[4] + 0x8000u) >> 16) | ((v[5] + 0x8000u) & 0xffff0000u);
            o.w = ((v[6] + 0x8000u) >> 16) | ((v[7] + 0x8000u) & 0xffff0000u);
            *(uint4*)&Asm[p][c0] = o;
        }
    }
    __syncthreads();

    // A-frags to registers: wave w owns pos w*32..w*32+31 (2 m-frags x 8 ks)
    short8 af[2][8];
    {
        int row0 = w * 32 + (L & 15), kq = (L >> 4) * 8;
        #pragma unroll
        for (int mf = 0; mf < 2; ++mf)
            #pragma unroll
            for (int ks = 0; ks < 8; ++ks)
                af[mf][ks] = *(const short8*)&Asm[row0 + mf * 16][ks * 32 + kq];
    }

    const short8* bp = (const short8*)cbfraw;
    float minv[2][4];
    #pragma unroll
    for (int r = 0; r < 4; ++r) { minv[0][r] = 3.4e38f; minv[1][r] = 3.4e38f; }

    auto loadB = [&](int nt, short8 (&dst)[8]) {
        #pragma unroll
        for (int ks = 0; ks < 8; ++ks) dst[ks] = bp[(nt * 8 + ks) * 64 + L];
    };
    auto pay = [](float d, unsigned nt) {
        return __uint_as_float((__float_as_uint(d) & ~63u) | nt);
    };
    auto compute_pair = [&](short8 (&bb)[2][8], int ntp) {
        f32x4 a00 = {0,0,0,0}, a10 = {0,0,0,0}, a01 = {0,0,0,0}, a11 = {0,0,0,0};
        #pragma unroll
        for (int ks = 0; ks < 8; ++ks) {
            a00 = __builtin_amdgcn_mfma_f32_16x16x32_bf16(af[0][ks], bb[0][ks], a00, 0, 0, 0);
            a10 = __builtin_amdgcn_mfma_f32_16x16x32_bf16(af[1][ks], bb[0][ks], a10, 0, 0, 0);
            a01 = __builtin_amdgcn_mfma_f32_16x16x32_bf16(af[0][ks], bb[1][ks], a01, 0, 0, 0);
            a11 = __builtin_amdgcn_mfma_f32_16x16x32_bf16(af[1][ks], bb[1][ks], a11, 0, 0, 0);
        }
        int col = L & 15;
        float c0v = cnS[ntp * 32 + col];
        float c1v = cnS[ntp * 32 + 16 + col];
        unsigned n0 = (unsigned)(ntp * 2), n1 = n0 + 1;
        #pragma unroll
        for (int r = 0; r < 4; ++r) {
            float d00 = pay(fmaf(-2.f, a00[r], c0v), n0);
            float d01 = pay(fmaf(-2.f, a01[r], c1v), n1);
            float d10 = pay(fmaf(-2.f, a10[r], c0v), n0);
            float d11 = pay(fmaf(-2.f, a11[r], c1v), n1);
            minv[0][r] = fminf(minv[0][r], fminf(d00, d01));
            minv[1][r] = fminf(minv[1][r], fminf(d10, d11));
        }
    };

    short8 bA[2][8], bB[2][8];
    loadB(0, bA[0]); loadB(1, bA[1]);
    for (int ntp = 0; ntp < 32; ntp += 2) {
        loadB(ntp * 2 + 2, bB[0]); loadB(ntp * 2 + 3, bB[1]);
        compute_pair(bA, ntp);
        if (ntp + 2 < 32) { loadB(ntp * 2 + 4, bA[0]); loadB(ntp * 2 + 5, bA[1]); }
        compute_pair(bB, ntp + 1);
    }

    // cross-lane reduce over the 16 code-columns; first-index tie-break
    const int col = L & 15, q = L >> 4;
    #pragma unroll
    for (int mf = 0; mf < 2; ++mf)
        #pragma unroll
        for (int r = 0; r < 4; ++r) {
            float v = minv[mf][r];
            int code = ((__float_as_int(v) & 63) << 4) + col;
            #pragma unroll
            for (int d = 1; d < 16; d <<= 1) {
                float ov = __shfl_xor(v, d, 64);
                int   oc = __shfl_xor(code, d, 64);
                if (ov < v || (ov == v && oc < code)) { v = ov; code = oc; }
            }
            if (col == 0)
                idx[blk * 128 + w * 32 + mf * 16 + q * 4 + r] = code;
        }
}

// ---------------------------------------------------------------------------
// Kernel 4: z_q scatter via coalesced codebook-row gather + LDS transpose,
// fused exact-fp32 loss = 1.25 * mean((q - z)^2).
__global__ __launch_bounds__(256) void scatter2(
        const float* __restrict__ z, const float* __restrict__ cb,
        const int* __restrict__ idx, float* __restrict__ out,
        float* __restrict__ loss) {
    __shared__ float Q[64][257];
    __shared__ float wsum[4];
    const int t = threadIdx.x, w = t >> 6, L = t & 63;
    const int n0 = blockIdx.x * 64;
    const int b = n0 >> 10, hw0 = n0 & 1023;

    #pragma unroll
    for (int rr = 0; rr < 16; ++rr) {
        int r = w * 16 + rr;
        int code = idx[n0 + r];
        float4 v = *(const float4*)(cb + ((size_t)code << 8) + (L << 2));
        float* qp = &Q[r][L << 2];
        qp[0] = v.x; qp[1] = v.y; qp[2] = v.z; qp[3] = v.w;
    }
    __syncthreads();

    float acc = 0.f;
    const int a = L & 15, qq = L >> 4;
    const size_t obase = ((size_t)b << 18) + hw0;
    #pragma unroll
    for (int i = 0; i < 16; ++i) {
        int c  = w * 64 + i * 4 + qq;
        int p0 = a * 4;
        float4 qv;
        qv.x = Q[p0 + 0][c]; qv.y = Q[p0 + 1][c];
        qv.z = Q[p0 + 2][c]; qv.w = Q[p0 + 3][c];
        size_t off = obase + ((size_t)c << 10) + p0;
        float4 zv = *(const float4*)(z + off);
        *(float4*)(out + off) = qv;
        float dx = qv.x - zv.x, dy = qv.y - zv.y;
        float dz2 = qv.z - zv.z, dw = qv.w - zv.w;
        acc += dx * dx + dy * dy + dz2 * dz2 + dw * dw;
    }
    #pragma unroll
    for (int off = 32; off; off >>= 1) acc += __shfl_down(acc, off, 64);
    if (L == 0) wsum[w] = acc;
    __syncthreads();
    if (t == 0)
        atomicAdd(loss, (wsum[0] + wsum[1] + wsum[2] + wsum[3]) * (1.25f / (float)NELEM));
}

// ---------------------------------------------------------------------------
extern "C" void kernel_launch(void* const* d_in, const int* in_sizes, int n_in,
                              void* d_out, int out_size, void* d_ws, size_t ws_size,
                              hipStream_t stream) {
    const float* z  = (const float*)d_in[0];
    const float* cb = (const float*)d_in[1];
    float* out  = (float*)d_out;
    float* cn   = (float*)d_ws;                                  // 4 KB
    int*   idxp = (int*)((char*)d_ws + 4096);                    // 128 KB
    uint4* cbf  = (uint4*)((char*)d_ws + 4096 + 131072);         // 512 KB
    float* loss = out + NELEM;

    hipMemsetAsync(loss, 0, sizeof(float), stream);
    cnorm_kernel<<<K_ / 4, 256, 0, stream>>>(cb, cn);
    prep_cb<<<128, 256, 0, stream>>>(cb, cbf);
    argmin_mfma<<<256, 256, 0, stream>>>(z, (const char*)cbf, cn, idxp);
    scatter2<<<512, 256, 0, stream>>>(z, cb, idxp, out, loss);
}

// Round 3
// 124.458 us; speedup vs baseline: 4.0726x; 1.0186x over previous
//
#include <hip/hip_runtime.h>

// VQ: z [32,256,32,32] f32, codebook [1024,256] f32
// out: z_q [32,256,32,32] f32 (8388608) then loss scalar f32 (1)
#define B_  32
#define C_  256
#define HW_ 1024
#define K_  1024
#define NELEM 8388608

typedef __attribute__((ext_vector_type(4))) float f32x4;
typedef unsigned long long ull;

// ---------------------------------------------------------------------------
// prep: codebook -> fp8 e4m3 (scaled x256) in B-fragment-linear order for
// mfma_f32_16x16x32_fp8_fp8, plus exact fp32 norms cn[k].
// frag g = nt*8+ks (512 B): lane L holds cb[nt*16+(L&15)][ks*32+(L>>4)*8+0..7]
__global__ __launch_bounds__(256) void prep_kernel(const float* __restrict__ cb,
                                                   uint2* __restrict__ cbf8,
                                                   float* __restrict__ cn) {
    const int t = threadIdx.x;
    const int gt = blockIdx.x * 256 + t;          // 0..32767
    const int L = gt & 63, g = gt >> 6;           // frag 0..511
    const int nt = g >> 3, ks = g & 7;
    const int code = nt * 16 + (L & 15);
    const int k0 = ks * 32 + (L >> 4) * 8;
    const float* s = cb + code * 256 + k0;
    float v[8];
    #pragma unroll
    for (int j = 0; j < 8; ++j) v[j] = s[j] * 256.0f;   // exact scale into e4m3 normal range
    int lo = 0, hi = 0;
    lo = __builtin_amdgcn_cvt_pk_fp8_f32(v[0], v[1], lo, false);
    lo = __builtin_amdgcn_cvt_pk_fp8_f32(v[2], v[3], lo, true);
    hi = __builtin_amdgcn_cvt_pk_fp8_f32(v[4], v[5], hi, false);
    hi = __builtin_amdgcn_cvt_pk_fp8_f32(v[6], v[7], hi, true);
    uint2 o; o.x = (unsigned)lo; o.y = (unsigned)hi;
    cbf8[g * 64 + L] = o;

    // norms: block handles codes blk*8..blk*8+7 (one wave -> 2 codes)
    const int w = t >> 6, lane = t & 63;
    #pragma unroll
    for (int cc = 0; cc < 2; ++cc) {
        int cd = blockIdx.x * 8 + w * 2 + cc;
        float4 qv = *(const float4*)(cb + cd * 256 + lane * 4);
        float s2 = qv.x*qv.x + qv.y*qv.y + qv.z*qv.z + qv.w*qv.w;
        #pragma unroll
        for (int off = 32; off; off >>= 1) s2 += __shfl_down(s2, off, 64);
        if (lane == 0) cn[cd] = s2;
    }
}

// ---------------------------------------------------------------------------
// Fused argmin + gather + transpose-store + loss.
// Grid 256 blocks (1/CU) x 256 thr. Block = 128 pos x all 1024 codes.
// A (z, fp8 x16) resident in regs; B chunks (4 nt = 16 KB) double-buffered in
// LDS shared by 4 waves. dist = cn - 2*dot; nt packed into 6 low mantissa bits.
// loss = 1.25/NELEM * sum(z^2_exact + dmin).
__global__ __launch_bounds__(256, 1) void vq_kernel(
        const float* __restrict__ z, const uint4* __restrict__ cbf8,
        const float* __restrict__ cb, const float* __restrict__ cn,
        float* __restrict__ out, float* __restrict__ loss) {
    __shared__ union {
        struct { float cn[1024]; uint4 B[2][1024]; } p1;   // 4 KB + 2x16 KB
        float Q[64][257];                                  // 65.8 KB (phase C/D)
    } S;
    __shared__ int codeS[128];
    __shared__ float wsum[4];

    const int t = threadIdx.x, w = t >> 6, L = t & 63;
    const int col = L & 15, q = L >> 4;
    const int blk = blockIdx.x;
    const int b = blk >> 3, hw0 = (blk & 7) << 7;

    // stage cn
    *(float4*)&S.p1.cn[t * 4] = *(const float4*)(cn + t * 4);

    // A-frags: wave w owns pos w*32..w*32+31 (2 m-frags). z scaled x16 -> fp8.
    // Exact fp32 z^2 accumulated from the same loads (each elem loaded once).
    ull af[2][8];
    float z2 = 0.f;
    const float* zb = z + ((size_t)b << 18) + hw0;
    #pragma unroll
    for (int mf = 0; mf < 2; ++mf) {
        const float* zp = zb + (w * 32 + mf * 16 + col) + ((q * 8) << 10);
        #pragma unroll
        for (int ks = 0; ks < 8; ++ks) {
            const float* sp = zp + ((ks * 32) << 10);
            float v[8];
            #pragma unroll
            for (int j = 0; j < 8; ++j) v[j] = sp[j << 10];
            #pragma unroll
            for (int j = 0; j < 8; ++j) z2 += v[j] * v[j];
            int lo = 0, hi = 0;
            lo = __builtin_amdgcn_cvt_pk_fp8_f32(v[0]*16.f, v[1]*16.f, lo, false);
            lo = __builtin_amdgcn_cvt_pk_fp8_f32(v[2]*16.f, v[3]*16.f, lo, true);
            hi = __builtin_amdgcn_cvt_pk_fp8_f32(v[4]*16.f, v[5]*16.f, hi, false);
            hi = __builtin_amdgcn_cvt_pk_fp8_f32(v[6]*16.f, v[7]*16.f, hi, true);
            af[mf][ks] = ((ull)(unsigned)hi << 32) | (unsigned)lo;
        }
    }

    // stage chunk 0 (frags 0..31, 16 KB): pure linear copy, coalesced uint4
    {
        uint4 st[4];
        #pragma unroll
        for (int i = 0; i < 4; ++i) st[i] = cbf8[(i << 8) + t];
        #pragma unroll
        for (int i = 0; i < 4; ++i) S.p1.B[0][(i << 8) + t] = st[i];
    }

    float minv[2][4];
    #pragma unroll
    for (int r = 0; r < 4; ++r) { minv[0][r] = 3.4e38f; minv[1][r] = 3.4e38f; }

    __syncthreads();

    const float SC = -4.8828125e-4f;   // -2 / (16*256)
    for (int it = 0; it < 16; ++it) {
        const int cur = it & 1;
        uint4 st2[4];
        if (it + 1 < 16) {
            #pragma unroll
            for (int i = 0; i < 4; ++i) st2[i] = cbf8[((it + 1) << 10) + (i << 8) + t];
        }
        const ull* bb = (const ull*)&S.p1.B[cur][0];
        #pragma unroll
        for (int np = 0; np < 2; ++np) {
            ull b0[8], b1[8];
            #pragma unroll
            for (int ks = 0; ks < 8; ++ks) {
                b0[ks] = bb[(np * 16 + ks) * 64 + L];       // lane-contiguous b64
                b1[ks] = bb[(np * 16 + 8 + ks) * 64 + L];
            }
            f32x4 a00 = {0,0,0,0}, a10 = {0,0,0,0}, a01 = {0,0,0,0}, a11 = {0,0,0,0};
            #pragma unroll
            for (int ks = 0; ks < 8; ++ks) {                // 4 independent chains
                a00 = __builtin_amdgcn_mfma_f32_16x16x32_fp8_fp8((long long)af[0][ks], (long long)b0[ks], a00, 0, 0, 0);
                a10 = __builtin_amdgcn_mfma_f32_16x16x32_fp8_fp8((long long)af[1][ks], (long long)b0[ks], a10, 0, 0, 0);
                a01 = __builtin_amdgcn_mfma_f32_16x16x32_fp8_fp8((long long)af[0][ks], (long long)b1[ks], a01, 0, 0, 0);
                a11 = __builtin_amdgcn_mfma_f32_16x16x32_fp8_fp8((long long)af[1][ks], (long long)b1[ks], a11, 0, 0, 0);
            }
            const int nt0 = it * 4 + np * 2;
            const float c0v = S.p1.cn[nt0 * 16 + col];
            const float c1v = S.p1.cn[nt0 * 16 + 16 + col];
            const unsigned pn0 = (unsigned)nt0, pn1 = (unsigned)(nt0 + 1);
            #pragma unroll
            for (int r = 0; r < 4; ++r) {
                float d00 = fmaf(SC, a00[r], c0v);
                float d01 = fmaf(SC, a01[r], c1v);
                float d10 = fmaf(SC, a10[r], c0v);
                float d11 = fmaf(SC, a11[r], c1v);
                d00 = __uint_as_float((__float_as_uint(d00) & ~63u) | pn0);
                d01 = __uint_as_float((__float_as_uint(d01) & ~63u) | pn1);
                d10 = __uint_as_float((__float_as_uint(d10) & ~63u) | pn0);
                d11 = __uint_as_float((__float_as_uint(d11) & ~63u) | pn1);
                minv[0][r] = fminf(minv[0][r], fminf(d00, d01));
                minv[1][r] = fminf(minv[1][r], fminf(d10, d11));
            }
        }
        if (it + 1 < 16) {
            #pragma unroll
            for (int i = 0; i < 4; ++i) S.p1.B[cur ^ 1][(i << 8) + t] = st2[i];
        }
        __syncthreads();
    }

    // cross-lane min over the 16 code-cols; emit per-pos code + dmin
    float dpart = 0.f;
    #pragma unroll
    for (int mf = 0; mf < 2; ++mf)
        #pragma unroll
        for (int r = 0; r < 4; ++r) {
            float v = minv[mf][r];
            int cd = ((__float_as_int(v) & 63) << 4) | col;
            #pragma unroll
            for (int d = 1; d < 16; d <<= 1) {
                float ov = __shfl_xor(v, d, 64);
                int   oc = __shfl_xor(cd, d, 64);
                if (ov < v) { v = ov; cd = oc; }
            }
            if (col == 0) {
                codeS[w * 32 + mf * 16 + q * 4 + r] = cd;
                dpart += __uint_as_float(__float_as_uint(v) & ~63u);
            }
        }

    // loss partial: exact z^2 + dmin
    float tot = z2 + dpart;
    #pragma unroll
    for (int off = 32; off; off >>= 1) tot += __shfl_down(tot, off, 64);
    if (L == 0) wsum[w] = tot;
    __syncthreads();
    if (t == 0)
        atomicAdd(loss, (wsum[0] + wsum[1] + wsum[2] + wsum[3]) * (1.25f / (float)NELEM));

    // Phase C/D: gather fp32 codebook rows, transpose through LDS, write out.
    const size_t obase0 = ((size_t)b << 18) + hw0;
    #pragma unroll
    for (int ch = 0; ch < 2; ++ch) {
        __syncthreads();
        #pragma unroll
        for (int rr = 0; rr < 16; ++rr) {
            int row = w * 16 + rr;
            int code = codeS[ch * 64 + row];
            float4 v = *(const float4*)(cb + ((size_t)code << 8) + (L << 2));
            float* qp = &S.Q[row][L << 2];
            qp[0] = v.x; qp[1] = v.y; qp[2] = v.z; qp[3] = v.w;
        }
        __syncthreads();
        #pragma unroll
        for (int i = 0; i < 16; ++i) {
            int c = w * 64 + i * 4 + q;
            int p0 = col * 4;
            float4 qv;
            qv.x = S.Q[p0 + 0][c]; qv.y = S.Q[p0 + 1][c];
            qv.z = S.Q[p0 + 2][c]; qv.w = S.Q[p0 + 3][c];
            *(float4*)(out + obase0 + (size_t)(ch * 64) + ((size_t)c << 10) + p0) = qv;
        }
    }
}

// ---------------------------------------------------------------------------
extern "C" void kernel_launch(void* const* d_in, const int* in_sizes, int n_in,
                              void* d_out, int out_size, void* d_ws, size_t ws_size,
                              hipStream_t stream) {
    const float* z  = (const float*)d_in[0];
    const float* cb = (const float*)d_in[1];
    float* out  = (float*)d_out;
    float* cn   = (float*)d_ws;                              // 4 KB
    uint2* cbf8 = (uint2*)((char*)d_ws + 4096);              // 256 KB
    float* loss = out + NELEM;

    hipMemsetAsync(loss, 0, sizeof(float), stream);
    prep_kernel<<<128, 256, 0, stream>>>(cb, cbf8, cn);
    vq_kernel<<<256, 256, 0, stream>>>(z, (const uint4*)cbf8, cb, cn, out, loss);
}

// Round 4
// 109.285 us; speedup vs baseline: 4.6381x; 1.1388x over previous
//
#include <hip/hip_runtime.h>

// VQ: z [32,256,32,32] f32, codebook [1024,256] f32
// out: z_q [32,256,32,32] f32 (8388608) then loss scalar f32 (1)
#define NELEM 8388608

typedef __attribute__((ext_vector_type(4))) float f32x4;
typedef unsigned long long ull;

// ---------------------------------------------------------------------------
// prep: codebook -> fp8 e4m3 (scaled x256, exact pow2) in B-fragment-linear
// order for mfma_f32_16x16x32_fp8_fp8, plus exact fp32 norms cn[k].
// frag g = nt*8+ks (512 B): lane L holds cb[nt*16+(L&15)][ks*32+(L>>4)*8+0..7]
__global__ __launch_bounds__(256) void prep_kernel(const float* __restrict__ cb,
                                                   uint2* __restrict__ cbf8,
                                                   float* __restrict__ cn) {
    const int t = threadIdx.x;
    const int gt = blockIdx.x * 256 + t;          // 0..32767
    const int L = gt & 63, g = gt >> 6;           // frag 0..511
    const int nt = g >> 3, ks = g & 7;
    const int code = nt * 16 + (L & 15);
    const int k0 = ks * 32 + (L >> 4) * 8;
    const float* s = cb + code * 256 + k0;
    float v[8];
    #pragma unroll
    for (int j = 0; j < 8; ++j) v[j] = s[j] * 256.0f;
    int lo = 0, hi = 0;
    lo = __builtin_amdgcn_cvt_pk_fp8_f32(v[0], v[1], lo, false);
    lo = __builtin_amdgcn_cvt_pk_fp8_f32(v[2], v[3], lo, true);
    hi = __builtin_amdgcn_cvt_pk_fp8_f32(v[4], v[5], hi, false);
    hi = __builtin_amdgcn_cvt_pk_fp8_f32(v[6], v[7], hi, true);
    uint2 o; o.x = (unsigned)lo; o.y = (unsigned)hi;
    cbf8[g * 64 + L] = o;

    const int w = t >> 6, lane = t & 63;
    #pragma unroll
    for (int cc = 0; cc < 2; ++cc) {
        int cd = blockIdx.x * 8 + w * 2 + cc;
        float4 qv = *(const float4*)(cb + cd * 256 + lane * 4);
        float s2 = qv.x*qv.x + qv.y*qv.y + qv.z*qv.z + qv.w*qv.w;
        #pragma unroll
        for (int off = 32; off; off >>= 1) s2 += __shfl_down(s2, off, 64);
        if (lane == 0) cn[cd] = s2;
    }
}

// ---------------------------------------------------------------------------
// Fused argmin + gather + transpose-store + loss.
// Grid 512 blocks x 256 thr, 2 blocks/CU (LDS 36 KB). Block = 64 pos x 1024
// codes, K=256 resident in regs (fp8 x16). B chunks (4 nt = 16 KB) double-
// buffered in LDS. dist = cn - 2*dot; nt packed into 6 low mantissa bits.
// loss = 1.25/NELEM * sum(z^2_exact + dmin).
__global__ __launch_bounds__(256, 2) void vq_kernel(
        const float* __restrict__ z, const uint4* __restrict__ cbf8,
        const float* __restrict__ cb, const float* __restrict__ cn,
        float* __restrict__ out, float* __restrict__ loss) {
    __shared__ union {
        struct { float cn[1024]; uint4 B[2][1024]; } p1;   // 4 + 2x16 KB
        float Q[32][257];                                  // 32.9 KB
    } S;
    __shared__ int codeS[64];
    __shared__ float wsum[4];

    const int t = threadIdx.x, w = t >> 6, L = t & 63;
    const int col = L & 15, q = L >> 4;
    const int blk = blockIdx.x;
    const int b = blk >> 4, hw0 = (blk & 15) << 6;

    // stage cn
    *(float4*)&S.p1.cn[t * 4] = *(const float4*)(cn + t * 4);

    // B chunk 0 global loads (issue early, store after A phase)
    uint4 st0[4];
    #pragma unroll
    for (int i = 0; i < 4; ++i) st0[i] = cbf8[(i << 8) + t];

    // A-frags: wave w owns pos w*16..w*16+15 (1 m-frag). z scaled x16 -> fp8.
    // Exact fp32 z^2 accumulated from the same loads.
    ull af[8];
    float z2 = 0.f;
    const float* zb = z + ((size_t)b << 18) + hw0;
    {
        const float* zp = zb + (w * 16 + col) + ((q * 8) << 10);
        #pragma unroll
        for (int ks = 0; ks < 8; ++ks) {
            const float* sp = zp + ((ks * 32) << 10);
            float v[8];
            #pragma unroll
            for (int j = 0; j < 8; ++j) v[j] = sp[j << 10];
            #pragma unroll
            for (int j = 0; j < 8; ++j) z2 += v[j] * v[j];
            int lo = 0, hi = 0;
            lo = __builtin_amdgcn_cvt_pk_fp8_f32(v[0]*16.f, v[1]*16.f, lo, false);
            lo = __builtin_amdgcn_cvt_pk_fp8_f32(v[2]*16.f, v[3]*16.f, lo, true);
            hi = __builtin_amdgcn_cvt_pk_fp8_f32(v[4]*16.f, v[5]*16.f, hi, false);
            hi = __builtin_amdgcn_cvt_pk_fp8_f32(v[6]*16.f, v[7]*16.f, hi, true);
            af[ks] = ((ull)(unsigned)hi << 32) | (unsigned)lo;
        }
    }

    #pragma unroll
    for (int i = 0; i < 4; ++i) S.p1.B[0][(i << 8) + t] = st0[i];

    float minv[4];
    #pragma unroll
    for (int r = 0; r < 4; ++r) minv[r] = 3.4e38f;

    __syncthreads();

    const float SC = -4.8828125e-4f;   // -2 / (16*256)
    for (int it = 0; it < 16; ++it) {
        const int cur = it & 1;
        uint4 st2[4];
        if (it < 15) {
            #pragma unroll
            for (int i = 0; i < 4; ++i) st2[i] = cbf8[((it + 1) << 10) + (i << 8) + t];
        }
        const ull* bb = (const ull*)&S.p1.B[cur][0];
        ull breg[4][8];
        #pragma unroll
        for (int n2 = 0; n2 < 4; ++n2)
            #pragma unroll
            for (int ks = 0; ks < 8; ++ks)
                breg[n2][ks] = bb[(n2 * 8 + ks) * 64 + L];

        f32x4 a0 = {0,0,0,0}, a1 = {0,0,0,0}, a2 = {0,0,0,0}, a3 = {0,0,0,0};
        #pragma unroll
        for (int ks = 0; ks < 8; ++ks) {            // 4 independent chains
            a0 = __builtin_amdgcn_mfma_f32_16x16x32_fp8_fp8((long long)af[ks], (long long)breg[0][ks], a0, 0, 0, 0);
            a1 = __builtin_amdgcn_mfma_f32_16x16x32_fp8_fp8((long long)af[ks], (long long)breg[1][ks], a1, 0, 0, 0);
            a2 = __builtin_amdgcn_mfma_f32_16x16x32_fp8_fp8((long long)af[ks], (long long)breg[2][ks], a2, 0, 0, 0);
            a3 = __builtin_amdgcn_mfma_f32_16x16x32_fp8_fp8((long long)af[ks], (long long)breg[3][ks], a3, 0, 0, 0);
        }
        const int ntb = it * 4;
        #pragma unroll
        for (int n2 = 0; n2 < 4; ++n2) {
            const f32x4& aa = (n2 == 0) ? a0 : (n2 == 1) ? a1 : (n2 == 2) ? a2 : a3;
            const float cnv = S.p1.cn[(ntb + n2) * 16 + col];
            const unsigned pn = (unsigned)(ntb + n2);
            #pragma unroll
            for (int r = 0; r < 4; ++r) {
                float d = fmaf(SC, aa[r], cnv);
                d = __uint_as_float((__float_as_uint(d) & ~63u) | pn);
                minv[r] = fminf(minv[r], d);
            }
        }
        if (it < 15) {
            #pragma unroll
            for (int i = 0; i < 4; ++i) S.p1.B[cur ^ 1][(i << 8) + t] = st2[i];
        }
        __syncthreads();
    }

    // cross-lane min over the 16 code-cols; emit per-pos code + dmin
    float dpart = 0.f;
    #pragma unroll
    for (int r = 0; r < 4; ++r) {
        float v = minv[r];
        int cd = ((__float_as_int(v) & 63) << 4) | col;
        #pragma unroll
        for (int d = 1; d < 16; d <<= 1) {
            float ov = __shfl_xor(v, d, 64);
            int   oc = __shfl_xor(cd, d, 64);
            if (ov < v || (ov == v && oc < cd)) { v = ov; cd = oc; }
        }
        if (col == 0) {
            codeS[w * 16 + q * 4 + r] = cd;
            dpart += __uint_as_float(__float_as_uint(v) & ~63u);
        }
    }

    float tot = z2 + dpart;
    #pragma unroll
    for (int off = 32; off; off >>= 1) tot += __shfl_down(tot, off, 64);
    if (L == 0) wsum[w] = tot;
    __syncthreads();
    if (t == 0)
        atomicAdd(loss, (wsum[0] + wsum[1] + wsum[2] + wsum[3]) * (1.25f / (float)NELEM));

    // Phase C/D: gather fp32 codebook rows (coalesced), transpose via LDS,
    // write out. Two 32-pos chunks so Q fits the 36 KB union.
    const size_t obase = ((size_t)b << 18) + hw0;
    const int pg = L & 7, cidx = L >> 3;
    #pragma unroll
    for (int ch = 0; ch < 2; ++ch) {
        __syncthreads();
        #pragma unroll
        for (int rr = 0; rr < 8; ++rr) {
            int row = w * 8 + rr;
            int code = codeS[ch * 32 + row];
            float4 v = *(const float4*)(cb + ((size_t)code << 8) + (L << 2));
            float* qp = &S.Q[row][L << 2];
            qp[0] = v.x; qp[1] = v.y; qp[2] = v.z; qp[3] = v.w;
        }
        __syncthreads();
        #pragma unroll
        for (int i = 0; i < 8; ++i) {
            int c = w * 64 + i * 8 + cidx;
            int p0 = pg * 4;
            float4 qv;
            qv.x = S.Q[p0 + 0][c]; qv.y = S.Q[p0 + 1][c];
            qv.z = S.Q[p0 + 2][c]; qv.w = S.Q[p0 + 3][c];
            *(float4*)(out + obase + ((size_t)c << 10) + ch * 32 + p0) = qv;
        }
    }
}

// ---------------------------------------------------------------------------
extern "C" void kernel_launch(void* const* d_in, const int* in_sizes, int n_in,
                              void* d_out, int out_size, void* d_ws, size_t ws_size,
                              hipStream_t stream) {
    const float* z  = (const float*)d_in[0];
    const float* cb = (const float*)d_in[1];
    float* out  = (float*)d_out;
    float* cn   = (float*)d_ws;                              // 4 KB
    uint2* cbf8 = (uint2*)((char*)d_ws + 4096);              // 256 KB
    float* loss = out + NELEM;

    hipMemsetAsync(loss, 0, sizeof(float), stream);
    prep_kernel<<<128, 256, 0, stream>>>(cb, cbf8, cn);
    vq_kernel<<<512, 256, 0, stream>>>(z, (const uint4*)cbf8, cb, cn, out, loss);
}